// Round 1
// baseline (534.244 us; speedup 1.0000x reference)
//
#include <hip/hip_runtime.h>
#include <hip/hip_bf16.h>
#include <stdint.h>

typedef float floatx4 __attribute__((ext_vector_type(4)));
typedef __bf16 bfx8 __attribute__((ext_vector_type(8)));

#define ATT_SCALE 0.08838834764831845f

__device__ __forceinline__ uint16_t f2bf(float f) {
  uint32_t u = __float_as_uint(f);
  return (uint16_t)((u + 0x7fffu + ((u >> 16) & 1u)) >> 16);
}
__device__ __forceinline__ float bf2f(uint32_t bits16) {
  return __uint_as_float(bits16 << 16);
}

typedef __attribute__((address_space(3))) uint32_t lds_u32;
typedef const __attribute__((address_space(1))) uint32_t glob_u32;

// async global->LDS, 16B per lane. LDS dest is wave-uniform base + lane*16.
__device__ __forceinline__ void async_copy16(void* lds, const void* g) {
  uint32_t loff = (uint32_t)(uintptr_t)lds;              // low 32 bits = LDS offset
  loff = (uint32_t)__builtin_amdgcn_readfirstlane((int)loff);
  lds_u32* lp = reinterpret_cast<lds_u32*>(loff);
  glob_u32* gp = reinterpret_cast<glob_u32*>((uintptr_t)g);
  __builtin_amdgcn_global_load_lds(gp, lp, 16, 0, 0);
}

// ---------------------------------------------------------------------------
// fp32 -> bf16 convert, 4 elems/thread
__global__ void cvt_kernel(const float* __restrict__ in, uint16_t* __restrict__ out, int n) {
  int i = (blockIdx.x * 256 + threadIdx.x) << 2;
  if (i >= n) return;
  const float4 v = *(const float4*)(in + i);
  uint32_t lo = (uint32_t)f2bf(v.x) | ((uint32_t)f2bf(v.y) << 16);
  uint32_t hi = (uint32_t)f2bf(v.z) | ((uint32_t)f2bf(v.w) << 16);
  *(uint2*)(out + i) = make_uint2(lo, hi);
}

// ---------------------------------------------------------------------------
// in-place RoPE on bf16 buffer laid out (token, ncols); one thread per pair.
// shift = log2(ncols/2). token rows are B*S with S=2048; pair index -> f = cp & 63.
__global__ void rope_kernel(uint32_t* __restrict__ buf, const float* __restrict__ freq,
                            int shift, int total) {
  int idx = blockIdx.x * 256 + threadIdx.x;
  if (idx >= total) return;
  int row = idx >> shift;
  int cp  = idx & ((1 << shift) - 1);
  int s = row & 2047;
  int f = cp & 63;
  float fr = freq[(s << 6) + f];
  float sn, c;
  sincosf(fr, &sn, &c);
  uint32_t u = buf[idx];
  float xr = bf2f(u & 0xffffu);
  float xi = bf2f(u >> 16);
  float orr = xr * c - xi * sn;
  float oi  = xr * sn + xi * c;
  buf[idx] = (uint32_t)f2bf(orr) | ((uint32_t)f2bf(oi) << 16);
}

// ---------------------------------------------------------------------------
// BT GEMM: C[M][N] = A[M x K] * W[N x K]^T (+bias). 128x128 tile, BK=64,
// 4 waves (2x2), 16x16x32 bf16 MFMA. LDS XOR-swizzled (both sides).
// MODE 0: QKV fused epilogue (Q/K bf16 token-major, V bf16 transposed d-major)
// MODE 1: fp32 out + bias
template <int MODE>
__global__ __launch_bounds__(256) void gemm_bt(
    const uint16_t* __restrict__ A,
    const uint16_t* __restrict__ Wq, const uint16_t* __restrict__ Wk,
    const uint16_t* __restrict__ Wv,
    const float* __restrict__ bq, const float* __restrict__ bk,
    const float* __restrict__ bv,
    uint16_t* __restrict__ Qo, uint16_t* __restrict__ Ko,
    uint16_t* __restrict__ Vt, float* __restrict__ Fo) {
  constexpr int Kd = 2048;
  const int tid  = threadIdx.x;
  const int w    = tid >> 6;
  const int lane = tid & 63;
  const int bm = blockIdx.x << 7;
  const int n0 = blockIdx.y << 7;

  const uint16_t* Wp;
  int wrow;
  if (MODE == 0) {
    if (n0 < 2048)      { Wp = Wq; wrow = n0; }
    else if (n0 < 2560) { Wp = Wk; wrow = n0 - 2048; }
    else                { Wp = Wv; wrow = n0 - 2560; }
  } else {
    Wp = Wq; wrow = n0;
  }

  __shared__ uint16_t As[128 * 64];
  __shared__ uint16_t Bs[128 * 64];
  char* AsB = (char*)As;
  char* BsB = (char*)Bs;

  floatx4 acc[4][4] = {};
  const int wr = (w >> 1) << 6;
  const int wc = (w & 1) << 6;

  const int sr  = lane >> 3;                 // row-within-8
  const int scb = ((lane & 7) ^ sr) << 4;    // inverse-swizzled source byte col

  const char* Aptr = (const char*)(A + (size_t)(bm + 32 * w + sr) * Kd) + scb;
  const char* Wptr = (const char*)(Wp + (size_t)(wrow + 32 * w + sr) * Kd) + scb;

  for (int k0 = 0; k0 < Kd; k0 += 64) {
#pragma unroll
    for (int i = 0; i < 4; ++i)
      async_copy16(AsB + (32 * w + 8 * i) * 128, Aptr + (size_t)(8 * i) * Kd * 2 + k0 * 2);
#pragma unroll
    for (int i = 0; i < 4; ++i)
      async_copy16(BsB + (32 * w + 8 * i) * 128, Wptr + (size_t)(8 * i) * Kd * 2 + k0 * 2);
    __syncthreads();
#pragma unroll
    for (int kk = 0; kk < 2; ++kk) {
      const int cb = (kk << 6) + ((lane >> 4) << 4);
      bfx8 af[4], bfr[4];
#pragma unroll
      for (int m = 0; m < 4; ++m) {
        int r = wr + (m << 4) + (lane & 15);
        af[m] = *(const bfx8*)(AsB + r * 128 + (cb ^ ((r & 7) << 4)));
      }
#pragma unroll
      for (int n = 0; n < 4; ++n) {
        int r = wc + (n << 4) + (lane & 15);
        bfr[n] = *(const bfx8*)(BsB + r * 128 + (cb ^ ((r & 7) << 4)));
      }
#pragma unroll
      for (int m = 0; m < 4; ++m)
#pragma unroll
        for (int n = 0; n < 4; ++n)
          acc[m][n] = __builtin_amdgcn_mfma_f32_16x16x32_bf16(af[m], bfr[n], acc[m][n], 0, 0, 0);
    }
    __syncthreads();
  }

  // epilogue: D row = (lane>>4)*4 + reg, col = lane&15
  const int rb = bm + wr + ((lane >> 4) << 2);
  const int cl = wc + (lane & 15);
#pragma unroll
  for (int n = 0; n < 4; ++n) {
    const int c = n0 + cl + (n << 4);
#pragma unroll
    for (int m = 0; m < 4; ++m) {
      const int r0 = rb + (m << 4);
      if constexpr (MODE == 1) {
        const float bias = bq[c];
#pragma unroll
        for (int j = 0; j < 4; ++j)
          Fo[(size_t)(r0 + j) * 2048 + c] = acc[m][n][j] + bias;
      } else {
        if (n0 < 2048) {
          const float bias = bq[c];
#pragma unroll
          for (int j = 0; j < 4; ++j)
            Qo[(size_t)(r0 + j) * 2048 + c] = f2bf(acc[m][n][j] + bias);
        } else if (n0 < 2560) {
          const int ck = c - 2048;
          const float bias = bk[ck];
#pragma unroll
          for (int j = 0; j < 4; ++j)
            Ko[(size_t)(r0 + j) * 512 + ck] = f2bf(acc[m][n][j] + bias);
        } else {
          const int cv = c - 2560;
          const float bias = bv[cv];
          const int b = r0 >> 11, s = r0 & 2047;
          const int kv = cv >> 7, dh = cv & 127;
          uint32_t lo = (uint32_t)f2bf(acc[m][n][0] + bias) | ((uint32_t)f2bf(acc[m][n][1] + bias) << 16);
          uint32_t hi = (uint32_t)f2bf(acc[m][n][2] + bias) | ((uint32_t)f2bf(acc[m][n][3] + bias) << 16);
          *(uint2*)(Vt + (size_t)(((b << 2) + kv) * 128 + dh) * 2048 + s) = make_uint2(lo, hi);
        }
      }
    }
  }
}

// ---------------------------------------------------------------------------
// Causal GQA flash attention. Block = 64 q-rows (4 waves x 16), K/V tiles of 64.
// Q bf16 (token, 2048); K bf16 (token, 512); Vt bf16 (b,kv,d,token); O bf16 (token, 2048).
__global__ __launch_bounds__(256) void attn_kernel(
    const uint16_t* __restrict__ Q, const uint16_t* __restrict__ Kb,
    const uint16_t* __restrict__ Vt, uint16_t* __restrict__ O) {
  const int qt  = blockIdx.x;
  const int h   = blockIdx.y;
  const int b   = blockIdx.z;
  const int kvh = h >> 2;
  const int tid  = threadIdx.x;
  const int w    = tid >> 6;
  const int lane = tid & 63;
  const int l15 = lane & 15;
  const int l4  = lane >> 4;
  const int qbase = qt << 6;

  __shared__ uint16_t Ks[64 * 128];
  __shared__ uint16_t Vs[128 * 64];
  __shared__ uint16_t Ps[4][16 * 64];
  char* KsB = (char*)Ks;
  char* VsB = (char*)Vs;
  char* PsB = (char*)(Ps[w]);

  // hoist Q fragments (A-operand): row = l15 within wave's 16 rows, k = kk*32 + l4*8
  bfx8 qf[4];
  {
    const size_t qrow = (size_t)(b * 2048 + qbase + (w << 4) + l15);
    const char* qp = (const char*)(Q + qrow * 2048 + h * 128 + l4 * 8);
#pragma unroll
    for (int kk = 0; kk < 4; ++kk) qf[kk] = *(const bfx8*)(qp + kk * 64);
  }

  floatx4 oacc[8] = {};
  float mrun[4], lrun[4];
#pragma unroll
  for (int j = 0; j < 4; ++j) { mrun[j] = -1e30f; lrun[j] = 0.0f; }

  for (int t = 0; t <= qt; ++t) {
    const int kb = t << 6;
    // stage K tile: 64 rows x 256B, swizzled
#pragma unroll
    for (int i = 0; i < 4; ++i) {
      const int base_r = 16 * w + 4 * i;
      const int r = base_r + l4;
      const int scb = (l15 << 4) ^ ((r & 7) << 4);
      const char* src = (const char*)Kb + ((size_t)(b * 2048 + kb + r) * 512 + kvh * 128) * 2 + scb;
      async_copy16(KsB + base_r * 256, src);
    }
    // stage V^T tile: 128 rows x 128B, swizzled
#pragma unroll
    for (int i = 0; i < 4; ++i) {
      const int base_r = 32 * w + 8 * i;
      const int r = base_r + (lane >> 3);
      const int scb = ((lane & 7) ^ ((lane >> 3) & 7)) << 4;
      const char* src = (const char*)Vt + ((size_t)(((b << 2) + kvh) * 128 + r) * 2048 + kb) * 2 + scb;
      async_copy16(VsB + base_r * 128, src);
    }
    __syncthreads();

    // S = Q K^T  (M=16 q rows, N=64 k cols, K=128)
    floatx4 sc[4] = {};
#pragma unroll
    for (int kk = 0; kk < 4; ++kk) {
      const int cb = (kk << 6) + (l4 << 4);
#pragma unroll
      for (int n = 0; n < 4; ++n) {
        const int r = (n << 4) + l15;
        bfx8 kf = *(const bfx8*)(KsB + r * 256 + (cb ^ ((r & 7) << 4)));
        sc[n] = __builtin_amdgcn_mfma_f32_16x16x32_bf16(qf[kk], kf, sc[n], 0, 0, 0);
      }
    }

    float p[4][4];
    const bool diag = (t == qt);
#pragma unroll
    for (int n = 0; n < 4; ++n) {
#pragma unroll
      for (int j = 0; j < 4; ++j) {
        float v = sc[n][j] * ATT_SCALE;
        if (diag) {
          const int col = kb + (n << 4) + l15;
          const int row = qbase + (w << 4) + (l4 << 2) + j;
          if (col > row) v = -1e30f;
        }
        p[n][j] = v;
      }
    }

    // online softmax per q-row (row = l4*4 + j, values across n frags and l15 lanes)
#pragma unroll
    for (int j = 0; j < 4; ++j) {
      float pm = fmaxf(fmaxf(p[0][j], p[1][j]), fmaxf(p[2][j], p[3][j]));
#pragma unroll
      for (int off = 8; off > 0; off >>= 1) pm = fmaxf(pm, __shfl_xor(pm, off, 64));
      const float mnew = fmaxf(mrun[j], pm);
      const float sf = __expf(mrun[j] - mnew);
      mrun[j] = mnew;
      float rs = 0.f;
#pragma unroll
      for (int n = 0; n < 4; ++n) {
        p[n][j] = __expf(p[n][j] - mnew);
        rs += p[n][j];
      }
#pragma unroll
      for (int off = 8; off > 0; off >>= 1) rs += __shfl_xor(rs, off, 64);
      lrun[j] = lrun[j] * sf + rs;
#pragma unroll
      for (int d = 0; d < 8; ++d) oacc[d][j] *= sf;
    }

    // P -> per-wave LDS (bf16), swizzled; D-layout write, A-layout read
#pragma unroll
    for (int n = 0; n < 4; ++n) {
      const int cbw = (n << 5) + (l15 << 1);
#pragma unroll
      for (int j = 0; j < 4; ++j) {
        const int r = (l4 << 2) + j;
        *(uint16_t*)(PsB + r * 128 + (cbw ^ ((r & 7) << 4))) = f2bf(p[n][j]);
      }
    }
    __syncthreads();

    // O += P V   (M=16 q rows, N=128 d, K=64 k cols)
#pragma unroll
    for (int kk = 0; kk < 2; ++kk) {
      const int cb = (kk << 6) + (l4 << 4);
      bfx8 pf = *(const bfx8*)(PsB + l15 * 128 + (cb ^ ((l15 & 7) << 4)));
#pragma unroll
      for (int d = 0; d < 8; ++d) {
        const int r = (d << 4) + l15;
        bfx8 vf = *(const bfx8*)(VsB + r * 128 + (cb ^ ((r & 7) << 4)));
        oacc[d] = __builtin_amdgcn_mfma_f32_16x16x32_bf16(pf, vf, oacc[d], 0, 0, 0);
      }
    }
    __syncthreads();
  }

  // epilogue: normalize and store bf16 (token, h*128 + d*16 + l15)
#pragma unroll
  for (int j = 0; j < 4; ++j) {
    const float inv = 1.0f / lrun[j];
    const size_t row = (size_t)(b * 2048 + qbase + (w << 4) + (l4 << 2) + j);
#pragma unroll
    for (int d = 0; d < 8; ++d) {
      const int c = h * 128 + (d << 4) + l15;
      O[row * 2048 + c] = f2bf(oacc[d][j] * inv);
    }
  }
}

// ---------------------------------------------------------------------------
extern "C" void kernel_launch(void* const* d_in, const int* in_sizes, int n_in,
                              void* d_out, int out_size, void* d_ws, size_t ws_size,
                              hipStream_t stream) {
  (void)in_sizes; (void)n_in; (void)out_size; (void)ws_size;
  const float* x         = (const float*)d_in[0];
  const float* rope_freq = (const float*)d_in[1];
  // d_in[2] = mask (implicit causal; unused)
  const float* wq_w = (const float*)d_in[3];
  const float* wq_b = (const float*)d_in[4];
  const float* wk_w = (const float*)d_in[5];
  const float* wk_b = (const float*)d_in[6];
  const float* wv_w = (const float*)d_in[7];
  const float* wv_b = (const float*)d_in[8];
  const float* wo_w = (const float*)d_in[9];
  const float* wo_b = (const float*)d_in[10];
  float* out = (float*)d_out;

  char* ws = (char*)d_ws;
  uint16_t* xbf = (uint16_t*)(ws + 0);          // 16 MB : x bf16 (4096,2048)
  uint16_t* wqb = (uint16_t*)(ws + 16777216);   //  8 MB
  uint16_t* wkb = (uint16_t*)(ws + 25165824);   //  2 MB
  uint16_t* wvb = (uint16_t*)(ws + 27262976);   //  2 MB
  uint16_t* wob = (uint16_t*)(ws + 29360128);   //  8 MB
  uint16_t* qbf = (uint16_t*)(ws + 37748736);   // 16 MB : Q (token,2048)
  uint16_t* kbf = (uint16_t*)(ws + 54525952);   //  4 MB : K (token,512)
  uint16_t* vtb = (uint16_t*)(ws + 58720256);   //  4 MB : V^T (b,kv,128,2048)
  uint16_t* att = (uint16_t*)(ws + 62914560);   // 16 MB : attn out (token,2048)

  cvt_kernel<<<8192, 256, 0, stream>>>(x, xbf, 8388608);
  cvt_kernel<<<4096, 256, 0, stream>>>(wq_w, wqb, 4194304);
  cvt_kernel<<<1024, 256, 0, stream>>>(wk_w, wkb, 1048576);
  cvt_kernel<<<1024, 256, 0, stream>>>(wv_w, wvb, 1048576);
  cvt_kernel<<<4096, 256, 0, stream>>>(wo_w, wob, 4194304);

  gemm_bt<0><<<dim3(32, 24), 256, 0, stream>>>(xbf, wqb, wkb, wvb, wq_b, wk_b, wv_b,
                                               qbf, kbf, vtb, nullptr);

  rope_kernel<<<16384, 256, 0, stream>>>((uint32_t*)qbf, rope_freq, 10, 4194304);
  rope_kernel<<<4096, 256, 0, stream>>>((uint32_t*)kbf, rope_freq, 8, 1048576);

  attn_kernel<<<dim3(32, 16, 2), 256, 0, stream>>>(qbf, kbf, vtb, att);

  gemm_bt<1><<<dim3(32, 16), 256, 0, stream>>>(att, wob, nullptr, nullptr, wo_b, nullptr,
                                               nullptr, nullptr, nullptr, nullptr, out);
}

// Round 2
// 368.015 us; speedup vs baseline: 1.4517x; 1.4517x over previous
//
#include <hip/hip_runtime.h>
#include <hip/hip_bf16.h>
#include <stdint.h>

typedef float floatx4 __attribute__((ext_vector_type(4)));
typedef __bf16 bfx8 __attribute__((ext_vector_type(8)));

#define ATT_SCALE 0.08838834764831845f

__device__ __forceinline__ uint16_t f2bf(float f) {
  uint32_t u = __float_as_uint(f);
  return (uint16_t)((u + 0x7fffu + ((u >> 16) & 1u)) >> 16);
}
__device__ __forceinline__ float bf2f(uint32_t bits16) {
  return __uint_as_float(bits16 << 16);
}

typedef __attribute__((address_space(3))) uint32_t lds_u32;
typedef const __attribute__((address_space(1))) uint32_t glob_u32;

// async global->LDS, 16B per lane. LDS dest is wave-uniform base + lane*16.
__device__ __forceinline__ void async_copy16(void* lds, const void* g) {
  uint32_t loff = (uint32_t)(uintptr_t)lds;              // low 32 bits = LDS offset
  loff = (uint32_t)__builtin_amdgcn_readfirstlane((int)loff);
  lds_u32* lp = reinterpret_cast<lds_u32*>(loff);
  glob_u32* gp = reinterpret_cast<glob_u32*>((uintptr_t)g);
  __builtin_amdgcn_global_load_lds(gp, lp, 16, 0, 0);
}

// ---------------------------------------------------------------------------
// fp32 -> bf16 convert, 4 elems/thread
__global__ void cvt_kernel(const float* __restrict__ in, uint16_t* __restrict__ out, int n) {
  int i = (blockIdx.x * 256 + threadIdx.x) << 2;
  if (i >= n) return;
  const float4 v = *(const float4*)(in + i);
  uint32_t lo = (uint32_t)f2bf(v.x) | ((uint32_t)f2bf(v.y) << 16);
  uint32_t hi = (uint32_t)f2bf(v.z) | ((uint32_t)f2bf(v.w) << 16);
  *(uint2*)(out + i) = make_uint2(lo, hi);
}

// ---------------------------------------------------------------------------
// in-place RoPE on bf16 buffer laid out (token, ncols); one thread per pair.
__global__ void rope_kernel(uint32_t* __restrict__ buf, const float* __restrict__ freq,
                            int shift, int total) {
  int idx = blockIdx.x * 256 + threadIdx.x;
  if (idx >= total) return;
  int row = idx >> shift;
  int cp  = idx & ((1 << shift) - 1);
  int s = row & 2047;
  int f = cp & 63;
  float fr = freq[(s << 6) + f];
  float sn, c;
  sincosf(fr, &sn, &c);
  uint32_t u = buf[idx];
  float xr = bf2f(u & 0xffffu);
  float xi = bf2f(u >> 16);
  float orr = xr * c - xi * sn;
  float oi  = xr * sn + xi * c;
  buf[idx] = (uint32_t)f2bf(orr) | ((uint32_t)f2bf(oi) << 16);
}

// ---------------------------------------------------------------------------
// BT GEMM: C[M][N] = A[M x K] * W[N x K]^T (+bias). 128x128 tile, BK=64,
// 4 waves (2x2), 16x16x32 bf16 MFMA. LDS XOR-swizzled (both sides).
template <int MODE>
__global__ __launch_bounds__(256) void gemm_bt(
    const uint16_t* __restrict__ A,
    const uint16_t* __restrict__ Wq, const uint16_t* __restrict__ Wk,
    const uint16_t* __restrict__ Wv,
    const float* __restrict__ bq, const float* __restrict__ bk,
    const float* __restrict__ bv,
    uint16_t* __restrict__ Qo, uint16_t* __restrict__ Ko,
    uint16_t* __restrict__ Vt, float* __restrict__ Fo) {
  constexpr int Kd = 2048;
  const int tid  = threadIdx.x;
  const int w    = tid >> 6;
  const int lane = tid & 63;
  const int bm = blockIdx.x << 7;
  const int n0 = blockIdx.y << 7;

  const uint16_t* Wp;
  int wrow;
  if (MODE == 0) {
    if (n0 < 2048)      { Wp = Wq; wrow = n0; }
    else if (n0 < 2560) { Wp = Wk; wrow = n0 - 2048; }
    else                { Wp = Wv; wrow = n0 - 2560; }
  } else {
    Wp = Wq; wrow = n0;
  }

  __shared__ uint16_t As[128 * 64];
  __shared__ uint16_t Bs[128 * 64];
  char* AsB = (char*)As;
  char* BsB = (char*)Bs;

  floatx4 acc[4][4] = {};
  const int wr = (w >> 1) << 6;
  const int wc = (w & 1) << 6;

  const int sr  = lane >> 3;
  const int scb = ((lane & 7) ^ sr) << 4;

  const char* Aptr = (const char*)(A + (size_t)(bm + 32 * w + sr) * Kd) + scb;
  const char* Wptr = (const char*)(Wp + (size_t)(wrow + 32 * w + sr) * Kd) + scb;

  for (int k0 = 0; k0 < Kd; k0 += 64) {
#pragma unroll
    for (int i = 0; i < 4; ++i)
      async_copy16(AsB + (32 * w + 8 * i) * 128, Aptr + (size_t)(8 * i) * Kd * 2 + k0 * 2);
#pragma unroll
    for (int i = 0; i < 4; ++i)
      async_copy16(BsB + (32 * w + 8 * i) * 128, Wptr + (size_t)(8 * i) * Kd * 2 + k0 * 2);
    __syncthreads();
#pragma unroll
    for (int kk = 0; kk < 2; ++kk) {
      const int cb = (kk << 6) + ((lane >> 4) << 4);
      bfx8 af[4], bfr[4];
#pragma unroll
      for (int m = 0; m < 4; ++m) {
        int r = wr + (m << 4) + (lane & 15);
        af[m] = *(const bfx8*)(AsB + r * 128 + (cb ^ ((r & 7) << 4)));
      }
#pragma unroll
      for (int n = 0; n < 4; ++n) {
        int r = wc + (n << 4) + (lane & 15);
        bfr[n] = *(const bfx8*)(BsB + r * 128 + (cb ^ ((r & 7) << 4)));
      }
#pragma unroll
      for (int m = 0; m < 4; ++m)
#pragma unroll
        for (int n = 0; n < 4; ++n)
          acc[m][n] = __builtin_amdgcn_mfma_f32_16x16x32_bf16(af[m], bfr[n], acc[m][n], 0, 0, 0);
    }
    __syncthreads();
  }

  const int rb = bm + wr + ((lane >> 4) << 2);
  const int cl = wc + (lane & 15);
#pragma unroll
  for (int n = 0; n < 4; ++n) {
    const int c = n0 + cl + (n << 4);
#pragma unroll
    for (int m = 0; m < 4; ++m) {
      const int r0 = rb + (m << 4);
      if constexpr (MODE == 1) {
        const float bias = bq[c];
#pragma unroll
        for (int j = 0; j < 4; ++j)
          Fo[(size_t)(r0 + j) * 2048 + c] = acc[m][n][j] + bias;
      } else {
        if (n0 < 2048) {
          const float bias = bq[c];
#pragma unroll
          for (int j = 0; j < 4; ++j)
            Qo[(size_t)(r0 + j) * 2048 + c] = f2bf(acc[m][n][j] + bias);
        } else if (n0 < 2560) {
          const int ck = c - 2048;
          const float bias = bk[ck];
#pragma unroll
          for (int j = 0; j < 4; ++j)
            Ko[(size_t)(r0 + j) * 512 + ck] = f2bf(acc[m][n][j] + bias);
        } else {
          const int cv = c - 2560;
          const float bias = bv[cv];
          const int b = r0 >> 11, s = r0 & 2047;
          const int kv = cv >> 7, dh = cv & 127;
          uint32_t lo = (uint32_t)f2bf(acc[m][n][0] + bias) | ((uint32_t)f2bf(acc[m][n][1] + bias) << 16);
          uint32_t hi = (uint32_t)f2bf(acc[m][n][2] + bias) | ((uint32_t)f2bf(acc[m][n][3] + bias) << 16);
          *(uint2*)(Vt + (size_t)(((b << 2) + kv) * 128 + dh) * 2048 + s) = make_uint2(lo, hi);
        }
      }
    }
  }
}

// ---------------------------------------------------------------------------
// Causal GQA flash attention, balanced pairs + double-buffered K/V staging.
// Block px handles q-tiles {px, 31-px} (33 iterations each, perfectly balanced).
// One __syncthreads per K-tile; prefetch of tile t+1 issued before compute of t.
__global__ __launch_bounds__(256) void attn_kernel(
    const uint16_t* __restrict__ Q, const uint16_t* __restrict__ Kb,
    const uint16_t* __restrict__ Vt, uint16_t* __restrict__ O) {
  const int px  = blockIdx.x;          // pair index 0..15
  const int h   = blockIdx.y;
  const int b   = blockIdx.z;
  const int kvh = h >> 2;
  const int tid  = threadIdx.x;
  const int w    = tid >> 6;
  const int lane = tid & 63;
  const int l15 = lane & 15;
  const int l4  = lane >> 4;

  __shared__ uint16_t Ks[2][64 * 128];
  __shared__ uint16_t Vs[2][128 * 64];
  __shared__ uint16_t Ps[4][16 * 64];
  char* PsB = (char*)(Ps[w]);

  // staging lane constants
  const int krow_off = l4;             // K: row within 4-row copy
  const int kscb = l15 << 4;           // K: byte col before swizzle
  const int vrow_off = lane >> 3;      // V: row within 8-row copy
  const int vscb = (lane & 7) << 4;

  auto stageK = [&](int buf, int t) {
    const int kb = t << 6;
#pragma unroll
    for (int i = 0; i < 4; ++i) {
      const int base_r = 16 * w + 4 * i;
      const int r = base_r + krow_off;
      const int scb = kscb ^ ((r & 7) << 4);
      const char* src = (const char*)Kb + ((size_t)(b * 2048 + kb + r) * 512 + kvh * 128) * 2 + scb;
      async_copy16((char*)(Ks[buf]) + base_r * 256, src);
    }
  };
  auto stageV = [&](int buf, int t) {
    const int kb = t << 6;
#pragma unroll
    for (int i = 0; i < 4; ++i) {
      const int base_r = 32 * w + 8 * i;
      const int r = base_r + vrow_off;
      const int scb = vscb ^ ((r & 7) << 4);
      const char* src = (const char*)Vt + ((size_t)(((b << 2) + kvh) * 128 + r) * 2048 + kb) * 2 + scb;
      async_copy16((char*)(Vs[buf]) + base_r * 128, src);
    }
  };

  for (int half = 0; half < 2; ++half) {
    const int qt = half ? (31 - px) : px;
    const int qbase = qt << 6;

    // hoist Q fragments
    bfx8 qf[4];
    {
      const size_t qrow = (size_t)(b * 2048 + qbase + (w << 4) + l15);
      const char* qp = (const char*)(Q + qrow * 2048 + h * 128 + l4 * 8);
#pragma unroll
      for (int kk = 0; kk < 4; ++kk) qf[kk] = *(const bfx8*)(qp + kk * 64);
    }

    floatx4 oacc[8] = {};
    float mrun[4], lrun[4];
#pragma unroll
    for (int j = 0; j < 4; ++j) { mrun[j] = -1e30f; lrun[j] = 0.0f; }

    stageK(0, 0);
    stageV(0, 0);
    __syncthreads();

    for (int t = 0; t <= qt; ++t) {
      const int cur = t & 1;
      if (t < qt) { stageK(cur ^ 1, t + 1); stageV(cur ^ 1, t + 1); }
      char* KsB = (char*)(Ks[cur]);
      char* VsB = (char*)(Vs[cur]);
      const int kb = t << 6;

      // S = Q K^T  (M=16 q rows, N=64 k cols, K=128)
      floatx4 sc[4] = {};
      __builtin_amdgcn_s_setprio(1);
#pragma unroll
      for (int kk = 0; kk < 4; ++kk) {
        const int cb = (kk << 6) + (l4 << 4);
#pragma unroll
        for (int n = 0; n < 4; ++n) {
          const int r = (n << 4) + l15;
          bfx8 kf = *(const bfx8*)(KsB + r * 256 + (cb ^ ((r & 7) << 4)));
          sc[n] = __builtin_amdgcn_mfma_f32_16x16x32_bf16(qf[kk], kf, sc[n], 0, 0, 0);
        }
      }
      __builtin_amdgcn_s_setprio(0);

      float p[4][4];
      const bool diag = (t == qt);
#pragma unroll
      for (int n = 0; n < 4; ++n) {
#pragma unroll
        for (int j = 0; j < 4; ++j) {
          float v = sc[n][j] * ATT_SCALE;
          if (diag) {
            const int col = kb + (n << 4) + l15;
            const int row = qbase + (w << 4) + (l4 << 2) + j;
            if (col > row) v = -1e30f;
          }
          p[n][j] = v;
        }
      }

      // online softmax: row max via 16-lane shfl reduce; sum kept per-lane partial
#pragma unroll
      for (int j = 0; j < 4; ++j) {
        float pm = fmaxf(fmaxf(p[0][j], p[1][j]), fmaxf(p[2][j], p[3][j]));
#pragma unroll
        for (int off = 8; off > 0; off >>= 1) pm = fmaxf(pm, __shfl_xor(pm, off, 64));
        const float mnew = fmaxf(mrun[j], pm);
        const float sf = __expf(mrun[j] - mnew);
        mrun[j] = mnew;
        float rs = 0.f;
#pragma unroll
        for (int n = 0; n < 4; ++n) {
          p[n][j] = __expf(p[n][j] - mnew);
          rs += p[n][j];
        }
        lrun[j] = lrun[j] * sf + rs;      // per-lane partial; reduced at epilogue
#pragma unroll
        for (int d = 0; d < 8; ++d) oacc[d][j] *= sf;
      }

      // P -> per-wave LDS (no barrier needed: wave-private buffer)
#pragma unroll
      for (int n = 0; n < 4; ++n) {
        const int cbw = (n << 5) + (l15 << 1);
#pragma unroll
        for (int j = 0; j < 4; ++j) {
          const int r = (l4 << 2) + j;
          *(uint16_t*)(PsB + r * 128 + (cbw ^ ((r & 7) << 4))) = f2bf(p[n][j]);
        }
      }

      // O += P V   (M=16 q rows, N=128 d, K=64 k cols)
      __builtin_amdgcn_s_setprio(1);
#pragma unroll
      for (int kk = 0; kk < 2; ++kk) {
        const int cb = (kk << 6) + (l4 << 4);
        bfx8 pf = *(const bfx8*)(PsB + l15 * 128 + (cb ^ ((l15 & 7) << 4)));
#pragma unroll
        for (int d = 0; d < 8; ++d) {
          const int r = (d << 4) + l15;
          bfx8 vf = *(const bfx8*)(VsB + r * 128 + (cb ^ ((r & 7) << 4)));
          oacc[d] = __builtin_amdgcn_mfma_f32_16x16x32_bf16(pf, vf, oacc[d], 0, 0, 0);
        }
      }
      __builtin_amdgcn_s_setprio(0);

      __syncthreads();   // waves done with buf[cur]; prefetch for t+1 drained
    }

    // epilogue: reduce lrun across 16 lanes, normalize, store bf16
#pragma unroll
    for (int j = 0; j < 4; ++j) {
      float l = lrun[j];
#pragma unroll
      for (int off = 8; off > 0; off >>= 1) l += __shfl_xor(l, off, 64);
      const float inv = 1.0f / l;
      const size_t row = (size_t)(b * 2048 + qbase + (w << 4) + (l4 << 2) + j);
#pragma unroll
      for (int d = 0; d < 8; ++d) {
        const int c = h * 128 + (d << 4) + l15;
        O[row * 2048 + c] = f2bf(oacc[d][j] * inv);
      }
    }
  }
}

// ---------------------------------------------------------------------------
extern "C" void kernel_launch(void* const* d_in, const int* in_sizes, int n_in,
                              void* d_out, int out_size, void* d_ws, size_t ws_size,
                              hipStream_t stream) {
  (void)in_sizes; (void)n_in; (void)out_size; (void)ws_size;
  const float* x         = (const float*)d_in[0];
  const float* rope_freq = (const float*)d_in[1];
  const float* wq_w = (const float*)d_in[3];
  const float* wq_b = (const float*)d_in[4];
  const float* wk_w = (const float*)d_in[5];
  const float* wk_b = (const float*)d_in[6];
  const float* wv_w = (const float*)d_in[7];
  const float* wv_b = (const float*)d_in[8];
  const float* wo_w = (const float*)d_in[9];
  const float* wo_b = (const float*)d_in[10];
  float* out = (float*)d_out;

  char* ws = (char*)d_ws;
  uint16_t* xbf = (uint16_t*)(ws + 0);          // 16 MB : x bf16 (4096,2048)
  uint16_t* wqb = (uint16_t*)(ws + 16777216);   //  8 MB
  uint16_t* wkb = (uint16_t*)(ws + 25165824);   //  2 MB
  uint16_t* wvb = (uint16_t*)(ws + 27262976);   //  2 MB
  uint16_t* wob = (uint16_t*)(ws + 29360128);   //  8 MB
  uint16_t* qbf = (uint16_t*)(ws + 37748736);   // 16 MB : Q (token,2048)
  uint16_t* kbf = (uint16_t*)(ws + 54525952);   //  4 MB : K (token,512)
  uint16_t* vtb = (uint16_t*)(ws + 58720256);   //  4 MB : V^T (b,kv,128,2048)
  uint16_t* att = (uint16_t*)(ws + 62914560);   // 16 MB : attn out (token,2048)

  cvt_kernel<<<8192, 256, 0, stream>>>(x, xbf, 8388608);
  cvt_kernel<<<4096, 256, 0, stream>>>(wq_w, wqb, 4194304);
  cvt_kernel<<<1024, 256, 0, stream>>>(wk_w, wkb, 1048576);
  cvt_kernel<<<1024, 256, 0, stream>>>(wv_w, wvb, 1048576);
  cvt_kernel<<<4096, 256, 0, stream>>>(wo_w, wob, 4194304);

  gemm_bt<0><<<dim3(32, 24), 256, 0, stream>>>(xbf, wqb, wkb, wvb, wq_b, wk_b, wv_b,
                                               qbf, kbf, vtb, nullptr);

  rope_kernel<<<16384, 256, 0, stream>>>((uint32_t*)qbf, rope_freq, 10, 4194304);
  rope_kernel<<<4096, 256, 0, stream>>>((uint32_t*)kbf, rope_freq, 8, 1048576);

  attn_kernel<<<dim3(16, 16, 2), 256, 0, stream>>>(qbf, kbf, vtb, att);

  gemm_bt<1><<<dim3(32, 16), 256, 0, stream>>>(att, wob, nullptr, nullptr, wo_b, nullptr,
                                               nullptr, nullptr, nullptr, nullptr, out);
}